// Round 3
// baseline (368.057 us; speedup 1.0000x reference)
//
#include <hip/hip_runtime.h>

#define NN 100000
#define BB 64
#define EE 1600000
#define FD 128
#define SLOTC 64                 // per-graph kept-row capacity (actual: ~1)
#define KSLOTS (BB * SLOTC)
#define EMAXE (1 << 20)
#define NWORDS (NN / 32)         // 3125 exactly
#define STR 391                  // ceil(NN/256)
#define GRIDB 512                // edge-scan blocks (arrival-counted); 2/CU -> all resident

// parallel lower_bound over sorted bidx: first idx in [0,NN] with bidx[idx]>=v.
// All 256 threads participate (contains __syncthreads).
__device__ __forceinline__ int plower(const int* __restrict__ bidx, int v,
                                      int tid, int* ired) {
    int p = tid * STR;                       // max 99705 < NN
    int val = bidx[p];
    ired[tid] = (val < v) ? tid : -1;
    __syncthreads();
    for (int s = 128; s > 0; s >>= 1) { if (tid < s) ired[tid] = max(ired[tid], ired[tid + s]); __syncthreads(); }
    int t0 = ired[0];
    __syncthreads();
    if (t0 < 0) return 0;
    int lo = t0 * STR;                       // bidx[lo] < v
    int hi = lo + STR; if (hi > NN) hi = NN; // answer in (lo, hi]
    int ans = hi;
    for (int q = lo + 1 + tid; q < hi; q += 256) {
        if (bidx[q] >= v) { ans = q; break; }// per-thread probes ascending
    }
    ired[tid] = ans;
    __syncthreads();
    for (int s = 128; s > 0; s >>= 1) { if (tid < s) ired[tid] = min(ired[tid], ired[tid + s]); __syncthreads(); }
    int r = ired[0];
    __syncthreads();
    return r;
}

// K1: one block per graph (round-0 proven). 3 passes: max, sum-exp, keep test;
// slot alloc; h0/deg init. Resets kecnt[0..2] (kept, cross, arrival).
__global__ __launch_bounds__(256) void k_scorekeep(
    const float2* __restrict__ x, const int* __restrict__ bidx,
    const float* __restrict__ tw,
    unsigned* __restrict__ kfbits, int* __restrict__ nslot,
    int* __restrict__ knt, float* __restrict__ degs, float2* __restrict__ h0s,
    int* __restrict__ kecnt)
{
    __shared__ int   ired[256];
    __shared__ float red[256];
    __shared__ int   klist[SLOTC];
    __shared__ int   lcnt;
    __shared__ float shv;
    int b = blockIdx.x, tid = threadIdx.x;
    if (tid == 0) { lcnt = 0; if (b == 0) { kecnt[0] = 0; kecnt[1] = 0; kecnt[2] = 0; } }
    int s0 = plower(bidx, b, tid, ired);
    int e0 = plower(bidx, b + 1, tid, ired);
    int L = e0 - s0;
    float w0 = tw[0], w1 = tw[1];

    // clear my slice of keep-bits. Interior words: plain store. Boundary words:
    // atomicAnd own-bits mask (disjoint vs neighbors -> commutes).
    if (L > 0) {
        int wlo = s0 >> 5, whi = (e0 - 1) >> 5;
        for (int w = wlo + tid; w <= whi; w += 256) {
            unsigned mask = 0xFFFFFFFFu;
            if (w == wlo) mask &= (0xFFFFFFFFu << (s0 & 31));
            if (w == whi) mask &= (0xFFFFFFFFu >> (31 - ((e0 - 1) & 31)));
            if (mask == 0xFFFFFFFFu) kfbits[w] = 0u;
            else atomicAnd(&kfbits[w], ~mask);
        }
    }

    // pass 1: max logit
    float mx = -3.4028235e38f;
    for (int j = tid; j < L; j += 256) {
        float2 v = x[s0 + j];
        mx = fmaxf(mx, v.x * w0 + v.y * w1);
    }
    red[tid] = mx; __syncthreads();
    for (int s = 128; s > 0; s >>= 1) { if (tid < s) red[tid] = fmaxf(red[tid], red[tid + s]); __syncthreads(); }
    if (tid == 0) shv = red[0];
    __syncthreads();
    float m = shv;

    // pass 2: S = sum exp(l - m)
    float sm = 0.f;
    for (int j = tid; j < L; j += 256) {
        float2 v = x[s0 + j];
        sm += expf(v.x * w0 + v.y * w1 - m);
    }
    red[tid] = sm; __syncthreads();
    for (int s = 128; s > 0; s >>= 1) { if (tid < s) red[tid] += red[tid + s]; __syncthreads(); }
    if (tid == 0) shv = red[0];
    __syncthreads();
    float S = shv;
    float thr = fminf(1.0f / S - 1e-7f, 0.1f);

    // pass 3: keep test + slot claim
    for (int j = tid; j < L; j += 256) {
        float2 v = x[s0 + j];
        float sc = expf(v.x * w0 + v.y * w1 - m) / S;
        if (sc > thr) {
            int l = atomicAdd(&lcnt, 1);
            if (l < SLOTC) klist[l] = j;
        }
    }
    __syncthreads();
    int nk = lcnt; if (nk > SLOTC) nk = SLOTC;
    if (tid == 0) knt[b] = nk;
    for (int l = tid; l < nk; l += 256) {
        int i = s0 + klist[l];
        float2 v = x[i];
        float sc = expf(v.x * w0 + v.y * w1 - m) / S;
        int slot = b * SLOTC + l;
        atomicOr(&kfbits[i >> 5], 1u << (i & 31));
        nslot[i] = slot;
        degs[slot] = 1.0f;                   // self-loop
        h0s[slot] = make_float2(v.x * sc, v.y * sc);
    }
}

// LDS overlay for K2's tail phase.
union ShTail {
    struct {
        float tileA[SLOTC * FD];             // 32 KB
        float tileB[SLOTC * FD];             // 32 KB
        float2 psl[SLOTC];
        float poolv[FD];
    } fast;
    struct {
        float bufA[SLOTC * FD];              // 32 KB (float2 acc / pool views)
        int   rows[KSLOTS];                  // 16 KB
        int   knt_s[BB];
        int   offs[BB + 1];
    } slow;
};

// K2: grid-stride edge scan + arrival election. The LAST BB arrivals each run
// one graph's tail IN PARALLEL (fast path, cross==0). Correctness fallback for
// cross!=0: block b==0 runs the round-2-validated whole-graph tail alone.
__global__ __launch_bounds__(256) void k_edge_tail(
    const int4* __restrict__ src4, const int* __restrict__ ei,
    const unsigned* __restrict__ kfbits, const int* __restrict__ nslot,
    float* __restrict__ degs, int* __restrict__ kedge, int* __restrict__ kecnt,
    const int* __restrict__ knt, const float2* __restrict__ h0s,
    const float* __restrict__ W1, const float* __restrict__ b1,
    const float* __restrict__ g1, const float* __restrict__ be1,
    const float* __restrict__ rm1, const float* __restrict__ rv1,
    const float* __restrict__ W2, const float* __restrict__ b2,
    const float* __restrict__ g2, const float* __restrict__ be2,
    const float* __restrict__ rm2, const float* __restrict__ rv2,
    const float* __restrict__ W3, const float* __restrict__ b3,
    const float* __restrict__ g3, const float* __restrict__ be3,
    const float* __restrict__ rm3, const float* __restrict__ rv3,
    const float* __restrict__ linW, const float* __restrict__ linb,
    float* __restrict__ hY, float* __restrict__ hAcc,
    float* __restrict__ out)
{
    __shared__ ShTail sh;
    __shared__ int ordS;
    int tid = threadIdx.x;

    // ---- phase 1: edge scan ----
    const int M = EE / 4;
    for (int t = blockIdx.x * 256 + tid; t < M; t += GRIDB * 256) {
        int4 s4 = src4[t];
        int ss[4] = {s4.x, s4.y, s4.z, s4.w};
        #pragma unroll
        for (int q = 0; q < 4; q++) {
            int s = ss[q];
            if ((kfbits[s >> 5] >> (s & 31)) & 1u) {
                int d = ei[EE + t * 4 + q];
                if ((kfbits[d >> 5] >> (d & 31)) & 1u) {
                    int ds = nslot[d], sl = nslot[s];
                    atomicAdd(&degs[ds], 1.0f);
                    int idx = atomicAdd(&kecnt[0], 1);
                    if (idx < EMAXE) { kedge[2 * idx] = sl; kedge[2 * idx + 1] = ds; }
                    if ((sl >> 6) != (ds >> 6)) atomicAdd(&kecnt[1], 1);
                }
            }
        }
    }

    // ---- arrival election: last BB arrivals run the tails ----
    __threadfence();                         // release this block's stores
    __syncthreads();
    if (tid == 0) ordS = atomicAdd(&kecnt[2], 1);
    __syncthreads();
    int ord = ordS;
    if (ord < GRIDB - BB) return;
    int b = ord - (GRIDB - BB);              // my graph

    // wait until ALL blocks have arrived (bounded by block-finish skew; the
    // stragglers never wait on us -> no deadlock; all 512 blocks co-resident
    // at 2 blocks/CU anyway).
    if (tid == 0) {
        while (__hip_atomic_load(&kecnt[2], __ATOMIC_RELAXED,
                                 __HIP_MEMORY_SCOPE_AGENT) < GRIDB)
            __builtin_amdgcn_s_sleep(2);
    }
    __syncthreads();
    __threadfence();                         // acquire: see all blocks' stores

    int ke = kecnt[0]; if (ke > EMAXE) ke = EMAXE;
    int cross = kecnt[1];

    if (cross == 0) {
        // ---- fast per-graph tail (round-0 k_tail_main fast path, verbatim) ----
        float* tileA = sh.fast.tileA;
        float* tileB = sh.fast.tileB;
        float2* psl  = sh.fast.psl;
        float* poolv = sh.fast.poolv;
        int nk = knt[b];

        for (int j = tid; j < SLOTC; j += 256) psl[j] = make_float2(0.f, 0.f);
        __syncthreads();
        for (int t = tid; t < ke; t += 256) {
            int d = kedge[2 * t + 1];
            if ((d >> 6) == b) {
                int s = kedge[2 * t];
                float nm = rsqrtf(degs[s]) * rsqrtf(degs[d]);
                float2 h = h0s[s];
                atomicAdd(&psl[d & 63].x, nm * h.x);
                atomicAdd(&psl[d & 63].y, nm * h.y);
            }
        }
        __syncthreads();
        // layer-1 node -> tileA = h1
        for (int j = tid; j < nk * FD; j += 256) {
            int ld = j >> 7, f = j & 127, slot = b * SLOTC + ld;
            float di = rsqrtf(degs[slot]), d2 = di * di;
            float2 h = h0s[slot];
            float a0 = psl[ld].x + d2 * h.x;
            float a1 = psl[ld].y + d2 * h.y;
            float v = a0 * W1[f] + a1 * W1[FD + f] + b1[f];
            v = fmaxf(v, 0.f);
            v = (v - rm1[f]) * rsqrtf(rv1[f] + 1e-5f) * g1[f] + be1[f];
            tileA[j] = v;
        }
        __syncthreads();
        // mm2: tileB = tileA @ W2
        for (int j = tid; j < nk * FD; j += 256) {
            int ld = j >> 7, f = j & 127;
            const float* xr = tileA + ld * FD;
            float acc = 0.f;
            #pragma unroll 8
            for (int k = 0; k < FD; k++) acc += xr[k] * W2[k * FD + f];
            tileB[j] = acc;
        }
        __syncthreads();
        // layer-2 scatter (LDS)
        for (int j = tid; j < nk * FD; j += 256) tileA[j] = 0.f;
        __syncthreads();
        for (long long idx = tid; idx < (long long)ke * FD; idx += 256) {
            int e = (int)(idx >> 7), f = (int)(idx & 127);
            int d = kedge[2 * e + 1];
            if ((d >> 6) == b) {
                int s = kedge[2 * e];            // cross==0 => s in graph b
                float nm = rsqrtf(degs[s]) * rsqrtf(degs[d]);
                atomicAdd(&tileA[(d & 63) * FD + f], nm * tileB[(s & 63) * FD + f]);
            }
        }
        __syncthreads();
        // bn2 -> tileA = h2
        for (int j = tid; j < nk * FD; j += 256) {
            int ld = j >> 7, f = j & 127, slot = b * SLOTC + ld;
            float di = rsqrtf(degs[slot]);
            float v = tileA[j] + di * di * tileB[j] + b2[f];
            v = fmaxf(v, 0.f);
            v = (v - rm2[f]) * rsqrtf(rv2[f] + 1e-5f) * g2[f] + be2[f];
            tileA[j] = v;
        }
        __syncthreads();
        // mm3: tileB = tileA @ W3
        for (int j = tid; j < nk * FD; j += 256) {
            int ld = j >> 7, f = j & 127;
            const float* xr = tileA + ld * FD;
            float acc = 0.f;
            #pragma unroll 8
            for (int k = 0; k < FD; k++) acc += xr[k] * W3[k * FD + f];
            tileB[j] = acc;
        }
        __syncthreads();
        // layer-3 scatter (LDS)
        for (int j = tid; j < nk * FD; j += 256) tileA[j] = 0.f;
        __syncthreads();
        for (long long idx = tid; idx < (long long)ke * FD; idx += 256) {
            int e = (int)(idx >> 7), f = (int)(idx & 127);
            int d = kedge[2 * e + 1];
            if ((d >> 6) == b) {
                int s = kedge[2 * e];
                float nm = rsqrtf(degs[s]) * rsqrtf(degs[d]);
                atomicAdd(&tileA[(d & 63) * FD + f], nm * tileB[(s & 63) * FD + f]);
            }
        }
        __syncthreads();
        // bn3 -> tileA = h3
        for (int j = tid; j < nk * FD; j += 256) {
            int ld = j >> 7, f = j & 127, slot = b * SLOTC + ld;
            float di = rsqrtf(degs[slot]);
            float v = tileA[j] + di * di * tileB[j] + b3[f];
            v = fmaxf(v, 0.f);
            v = (v - rm3[f]) * rsqrtf(rv3[f] + 1e-5f) * g3[f] + be3[f];
            tileA[j] = v;
        }
        __syncthreads();
        // pool + linear + log_softmax
        for (int f = tid; f < FD; f += 256) {
            float mx = -3.4028235e38f;
            for (int ld = 0; ld < nk; ld++) mx = fmaxf(mx, tileA[ld * FD + f]);
            poolv[f] = mx;
        }
        __syncthreads();
        if (tid == 0) {
            float z0 = linb[0], z1 = linb[1], z2 = linb[2];
            for (int f = 0; f < FD; f++) {
                float pv = poolv[f];
                z0 += pv * linW[f * 3 + 0];
                z1 += pv * linW[f * 3 + 1];
                z2 += pv * linW[f * 3 + 2];
            }
            float m = fmaxf(z0, fmaxf(z1, z2));
            float l = m + logf(expf(z0 - m) + expf(z1 - m) + expf(z2 - m));
            out[b * 3 + 0] = z0 - l;
            out[b * 3 + 1] = z1 - l;
            out[b * 3 + 2] = z2 - l;
        }
        return;
    }

    // ---- slow fallback (cross-graph kept edges; validated round-2 path).
    // Only one block proceeds; others done.
    if (b != 0) return;
    {
        float* bufA = sh.slow.bufA;
        int*   rows = sh.slow.rows;
        int*   knt_s = sh.slow.knt_s;
        int*   offs = sh.slow.offs;

        if (tid < BB) knt_s[tid] = knt[tid];
        __syncthreads();
        if (tid == 0) {
            int acc = 0;
            for (int g = 0; g < BB; g++) { offs[g] = acc; acc += knt_s[g]; }
            offs[BB] = acc;
        }
        __syncthreads();
        int Rtot = offs[BB];
        for (int g = tid; g < BB; g += 256)
            for (int l = 0; l < knt_s[g]; l++) rows[offs[g] + l] = g * SLOTC + l;
        __syncthreads();
        int RT = Rtot * FD;

        float2* acc2 = (float2*)bufA;
        for (int r = tid; r < Rtot; r += 256) acc2[rows[r]] = make_float2(0.f, 0.f);
        __syncthreads();
        for (int t = tid; t < ke; t += 256) {
            int s = kedge[2 * t], d = kedge[2 * t + 1];
            float nm = rsqrtf(degs[s]) * rsqrtf(degs[d]);
            float2 h = h0s[s];
            atomicAdd(&acc2[d].x, nm * h.x);
            atomicAdd(&acc2[d].y, nm * h.y);
        }
        __syncthreads();
        for (int j = tid; j < RT; j += 256) {
            int r = j >> 7, f = j & 127, slot = rows[r];
            float di = rsqrtf(degs[slot]), d2 = di * di;
            float2 h = h0s[slot];
            float a0 = acc2[slot].x + d2 * h.x;
            float a1 = acc2[slot].y + d2 * h.y;
            float v = a0 * W1[f] + a1 * W1[FD + f] + b1[f];
            v = fmaxf(v, 0.f);
            v = (v - rm1[f]) * rsqrtf(rv1[f] + 1e-5f) * g1[f] + be1[f];
            hAcc[slot * FD + f] = v;
        }
        __syncthreads();
        for (int j = tid; j < RT; j += 256) {
            int r = j >> 7, f = j & 127, slot = rows[r];
            const float* xr = hAcc + slot * FD;
            float acc = 0.f;
            #pragma unroll 8
            for (int k = 0; k < FD; k++) acc += xr[k] * W2[k * FD + f];
            hY[slot * FD + f] = acc;
        }
        __syncthreads();
        for (int j = tid; j < RT; j += 256) hAcc[rows[j >> 7] * FD + (j & 127)] = 0.f;
        __syncthreads();
        for (long long idx = tid; idx < (long long)ke * FD; idx += 256) {
            int e = (int)(idx >> 7), f = (int)(idx & 127);
            int s = kedge[2 * e], d = kedge[2 * e + 1];
            float nm = rsqrtf(degs[s]) * rsqrtf(degs[d]);
            atomicAdd(&hAcc[d * FD + f], nm * hY[s * FD + f]);
        }
        __syncthreads();
        for (int j = tid; j < RT; j += 256) {
            int r = j >> 7, f = j & 127, slot = rows[r];
            float di = rsqrtf(degs[slot]);
            float v = hAcc[slot * FD + f] + di * di * hY[slot * FD + f] + b2[f];
            v = fmaxf(v, 0.f);
            v = (v - rm2[f]) * rsqrtf(rv2[f] + 1e-5f) * g2[f] + be2[f];
            hAcc[slot * FD + f] = v;
        }
        __syncthreads();
        for (int j = tid; j < RT; j += 256) {
            int r = j >> 7, f = j & 127, slot = rows[r];
            const float* xr = hAcc + slot * FD;
            float acc = 0.f;
            #pragma unroll 8
            for (int k = 0; k < FD; k++) acc += xr[k] * W3[k * FD + f];
            hY[slot * FD + f] = acc;
        }
        __syncthreads();
        for (int j = tid; j < RT; j += 256) hAcc[rows[j >> 7] * FD + (j & 127)] = 0.f;
        __syncthreads();
        for (long long idx = tid; idx < (long long)ke * FD; idx += 256) {
            int e = (int)(idx >> 7), f = (int)(idx & 127);
            int s = kedge[2 * e], d = kedge[2 * e + 1];
            float nm = rsqrtf(degs[s]) * rsqrtf(degs[d]);
            atomicAdd(&hAcc[d * FD + f], nm * hY[s * FD + f]);
        }
        __syncthreads();
        for (int j = tid; j < RT; j += 256) {
            int r = j >> 7, f = j & 127, slot = rows[r];
            float di = rsqrtf(degs[slot]);
            float v = hAcc[slot * FD + f] + di * di * hY[slot * FD + f] + b3[f];
            v = fmaxf(v, 0.f);
            v = (v - rm3[f]) * rsqrtf(rv3[f] + 1e-5f) * g3[f] + be3[f];
            hAcc[slot * FD + f] = v;
        }
        __syncthreads();
        float* pool = bufA;
        for (int j = tid; j < BB * FD; j += 256) {
            int g = j >> 7, f = j & 127;
            float mx = -3.4028235e38f;
            int nk = knt_s[g];
            for (int l = 0; l < nk; l++) mx = fmaxf(mx, hAcc[(g * SLOTC + l) * FD + f]);
            pool[j] = mx;
        }
        __syncthreads();
        if (tid < BB) {
            int g = tid;
            float z0 = linb[0], z1 = linb[1], z2 = linb[2];
            for (int f = 0; f < FD; f++) {
                float pv = pool[g * FD + f];
                z0 += pv * linW[f * 3 + 0];
                z1 += pv * linW[f * 3 + 1];
                z2 += pv * linW[f * 3 + 2];
            }
            float m = fmaxf(z0, fmaxf(z1, z2));
            float l = m + logf(expf(z0 - m) + expf(z1 - m) + expf(z2 - m));
            out[g * 3 + 0] = z0 - l;
            out[g * 3 + 1] = z1 - l;
            out[g * 3 + 2] = z2 - l;
        }
    }
}

extern "C" void kernel_launch(void* const* d_in, const int* in_sizes, int n_in,
                              void* d_out, int out_size, void* d_ws, size_t ws_size,
                              hipStream_t stream) {
    (void)in_sizes; (void)n_in; (void)out_size; (void)ws_size;
    const float* x    = (const float*)d_in[0];
    const int*   ei   = (const int*)d_in[1];
    const int*   bidx = (const int*)d_in[2];
    const float* tw   = (const float*)d_in[3];
    const float* W1 = (const float*)d_in[4],  *b1 = (const float*)d_in[5],  *g1 = (const float*)d_in[6];
    const float* be1= (const float*)d_in[7],  *rm1= (const float*)d_in[8],  *rv1= (const float*)d_in[9];
    const float* W2 = (const float*)d_in[10], *b2 = (const float*)d_in[11], *g2 = (const float*)d_in[12];
    const float* be2= (const float*)d_in[13], *rm2= (const float*)d_in[14], *rv2= (const float*)d_in[15];
    const float* W3 = (const float*)d_in[16], *b3 = (const float*)d_in[17], *g3 = (const float*)d_in[18];
    const float* be3= (const float*)d_in[19], *rm3= (const float*)d_in[20], *rv3= (const float*)d_in[21];
    const float* linW = (const float*)d_in[22], *linb = (const float*)d_in[23];
    float* out = (float*)d_out;

    char* w = (char*)d_ws;
    auto take = [&](size_t bytes) { char* r = w; w += (bytes + 255) & ~(size_t)255; return r; };
    int*      kecnt  = (int*)take(16);        // [0]=kept, [1]=cross, [2]=arrival
    int*      knt    = (int*)take((size_t)BB * 4);
    unsigned* kfbits = (unsigned*)take((size_t)NWORDS * 4);
    int*      nslot  = (int*)take((size_t)NN * 4);
    float*    degs   = (float*)take((size_t)KSLOTS * 4);
    float2*   h0s    = (float2*)take((size_t)KSLOTS * 8);
    int*      kedge  = (int*)take((size_t)EMAXE * 8);
    float*    hY     = (float*)take((size_t)KSLOTS * FD * 4);
    float*    hAcc   = (float*)take((size_t)KSLOTS * FD * 4);

    k_scorekeep<<<BB, 256, 0, stream>>>((const float2*)x, bidx, tw,
                                        kfbits, nslot, knt, degs, h0s, kecnt);
    k_edge_tail<<<GRIDB, 256, 0, stream>>>((const int4*)ei, ei, kfbits, nslot,
                                           degs, kedge, kecnt, knt, h0s,
                                           W1, b1, g1, be1, rm1, rv1,
                                           W2, b2, g2, be2, rm2, rv2,
                                           W3, b3, g3, be3, rm3, rv3,
                                           linW, linb, hY, hAcc, out);
}

// Round 4
// 149.094 us; speedup vs baseline: 2.4686x; 2.4686x over previous
//
#include <hip/hip_runtime.h>

#define NN 100000
#define BB 64
#define EE 1600000
#define FD 128
#define SLOTC 64                 // per-graph kept-row capacity (actual: ~1)
#define KSLOTS (BB * SLOTC)
#define EMAXE (1 << 20)
#define NWORDS (NN / 32)         // 3125 exactly (100000 % 32 == 0)
#define STR 391                  // ceil(NN/256)

// parallel lower_bound over sorted bidx: first idx in [0,NN] with bidx[idx]>=v.
// All 256 threads participate (contains __syncthreads).
__device__ __forceinline__ int plower(const int* __restrict__ bidx, int v,
                                      int tid, int* ired) {
    int p = tid * STR;                       // max 99705 < NN
    int val = bidx[p];
    ired[tid] = (val < v) ? tid : -1;
    __syncthreads();
    for (int s = 128; s > 0; s >>= 1) { if (tid < s) ired[tid] = max(ired[tid], ired[tid + s]); __syncthreads(); }
    int t0 = ired[0];
    __syncthreads();
    if (t0 < 0) return 0;
    int lo = t0 * STR;                       // bidx[lo] < v
    int hi = lo + STR; if (hi > NN) hi = NN; // answer in (lo, hi]
    int ans = hi;
    for (int q = lo + 1 + tid; q < hi; q += 256) {
        if (bidx[q] >= v) { ans = q; break; }// per-thread probes ascending
    }
    ired[tid] = ans;
    __syncthreads();
    for (int s = 128; s > 0; s >>= 1) { if (tid < s) ired[tid] = min(ired[tid], ired[tid + s]); __syncthreads(); }
    int r = ired[0];
    __syncthreads();
    return r;
}

// K1 (round-0 verbatim): one block per graph. 3 passes: max, sum-exp, keep
// test; slot alloc; h0/deg init.
__global__ __launch_bounds__(256) void k_scorekeep(
    const float2* __restrict__ x, const int* __restrict__ bidx,
    const float* __restrict__ tw,
    unsigned* __restrict__ kfbits, int* __restrict__ nslot,
    int* __restrict__ knt, float* __restrict__ degs, float2* __restrict__ h0s,
    int* __restrict__ kecnt)
{
    __shared__ int   ired[256];
    __shared__ float red[256];
    __shared__ int   klist[SLOTC];
    __shared__ int   lcnt;
    __shared__ float shv;
    int b = blockIdx.x, tid = threadIdx.x;
    if (tid == 0) { lcnt = 0; if (b == 0) { kecnt[0] = 0; kecnt[1] = 0; } }
    int s0 = plower(bidx, b, tid, ired);
    int e0 = plower(bidx, b + 1, tid, ired);
    int L = e0 - s0;
    float w0 = tw[0], w1 = tw[1];

    // clear my slice of keep-bits. Interior words: plain store. Boundary words:
    // atomicAnd own-bits mask (disjoint vs neighbors -> commutes).
    if (L > 0) {
        int wlo = s0 >> 5, whi = (e0 - 1) >> 5;
        for (int w = wlo + tid; w <= whi; w += 256) {
            unsigned mask = 0xFFFFFFFFu;
            if (w == wlo) mask &= (0xFFFFFFFFu << (s0 & 31));
            if (w == whi) mask &= (0xFFFFFFFFu >> (31 - ((e0 - 1) & 31)));
            if (mask == 0xFFFFFFFFu) kfbits[w] = 0u;
            else atomicAnd(&kfbits[w], ~mask);
        }
    }

    // pass 1: max logit
    float mx = -3.4028235e38f;
    for (int j = tid; j < L; j += 256) {
        float2 v = x[s0 + j];
        mx = fmaxf(mx, v.x * w0 + v.y * w1);
    }
    red[tid] = mx; __syncthreads();
    for (int s = 128; s > 0; s >>= 1) { if (tid < s) red[tid] = fmaxf(red[tid], red[tid + s]); __syncthreads(); }
    if (tid == 0) shv = red[0];
    __syncthreads();
    float m = shv;

    // pass 2: S = sum exp(l - m)
    float sm = 0.f;
    for (int j = tid; j < L; j += 256) {
        float2 v = x[s0 + j];
        sm += expf(v.x * w0 + v.y * w1 - m);
    }
    red[tid] = sm; __syncthreads();
    for (int s = 128; s > 0; s >>= 1) { if (tid < s) red[tid] += red[tid + s]; __syncthreads(); }
    if (tid == 0) shv = red[0];
    __syncthreads();
    float S = shv;
    float thr = fminf(1.0f / S - 1e-7f, 0.1f);

    // pass 3: keep test + slot claim
    for (int j = tid; j < L; j += 256) {
        float2 v = x[s0 + j];
        float sc = expf(v.x * w0 + v.y * w1 - m) / S;
        if (sc > thr) {
            int l = atomicAdd(&lcnt, 1);
            if (l < SLOTC) klist[l] = j;
        }
    }
    __syncthreads();
    int nk = lcnt; if (nk > SLOTC) nk = SLOTC;
    if (tid == 0) knt[b] = nk;
    for (int l = tid; l < nk; l += 256) {
        int i = s0 + klist[l];
        float2 v = x[i];
        float sc = expf(v.x * w0 + v.y * w1 - m) / S;
        int slot = b * SLOTC + l;
        atomicOr(&kfbits[i >> 5], 1u << (i & 31));
        nslot[i] = slot;
        degs[slot] = 1.0f;                   // self-loop
        h0s[slot] = make_float2(v.x * sc, v.y * sc);
    }
}

// K2 (round-0 verbatim): edge scan, 4 edges/thread; bitmap L1-resident; dst
// probed only on src-kept. Counts total and cross-graph kept edges.
__global__ void k_edges(const int4* __restrict__ src4, const int* __restrict__ ei,
                        const unsigned* __restrict__ kfbits, const int* __restrict__ nslot,
                        float* __restrict__ degs, int* __restrict__ kedge,
                        int* __restrict__ kecnt) {
    int t = blockIdx.x * 256 + threadIdx.x;
    if (t * 4 >= EE) return;
    int4 s4 = src4[t];
    int ss[4] = {s4.x, s4.y, s4.z, s4.w};
    #pragma unroll
    for (int q = 0; q < 4; q++) {
        int s = ss[q];
        if ((kfbits[s >> 5] >> (s & 31)) & 1u) {
            int d = ei[EE + t * 4 + q];
            if ((kfbits[d >> 5] >> (d & 31)) & 1u) {
                int ds = nslot[d], sl = nslot[s];
                atomicAdd(&degs[ds], 1.0f);
                int idx = atomicAdd(&kecnt[0], 1);
                if (idx < EMAXE) { kedge[2 * idx] = sl; kedge[2 * idx + 1] = ds; }
                if ((sl >> 6) != (ds >> 6)) atomicAdd(&kecnt[1], 1);
            }
        }
    }
}

// K3: one block per graph. Fast path (cross==0, the actual case) is round-0
// k_tail_main byte-for-byte. Generic path (cross!=0) is now SELF-SUFFICIENT:
// foreign hY/hYB rows are recomputed on demand from h0s/degs/kedge (depth-2
// recompute) -> no second kernel, no global hY buffer.
__global__ __launch_bounds__(256) void k_tail(
    const float* __restrict__ degs, const float2* __restrict__ h0s,
    const int* __restrict__ kedge, const int* __restrict__ kecnt,
    const int* __restrict__ knt,
    const float* __restrict__ W1, const float* __restrict__ b1,
    const float* __restrict__ g1, const float* __restrict__ be1,
    const float* __restrict__ rm1, const float* __restrict__ rv1,
    const float* __restrict__ W2, const float* __restrict__ b2,
    const float* __restrict__ g2, const float* __restrict__ be2,
    const float* __restrict__ rm2, const float* __restrict__ rv2,
    const float* __restrict__ W3, const float* __restrict__ b3,
    const float* __restrict__ g3, const float* __restrict__ be3,
    const float* __restrict__ rm3, const float* __restrict__ rv3,
    const float* __restrict__ linW, const float* __restrict__ linb,
    float* __restrict__ out)
{
    __shared__ float tileA[SLOTC * FD];      // 32 KB
    __shared__ float tileB[SLOTC * FD];      // 32 KB
    __shared__ float tileC[SLOTC * FD];      // 32 KB (generic-path agg3 only)
    __shared__ float2 psl[SLOTC];
    __shared__ float poolv[FD];
    // generic-path row scratch (unused on fast path):
    __shared__ float rowT[FD];               // h1 scratch inside hY_row
    __shared__ float rowY[FD];               // hY(s) output
    __shared__ float rowAgg[FD];             // agg2 inside hYB_row
    __shared__ float rowH2[FD];              // h2(s) inside hYB_row
    __shared__ float rowB[FD];               // hYB(s) output
    __shared__ float2 aggs;                  // scalar layer-1 agg
    __shared__ int keS;
    int b = blockIdx.x, tid = threadIdx.x;
    if (tid == 0) { int k = kecnt[0]; keS = k > EMAXE ? EMAXE : k; }
    for (int j = tid; j < SLOTC; j += 256) psl[j] = make_float2(0.f, 0.f);
    __syncthreads();
    int ke = keS, nk = knt[b], cross = kecnt[1];

    // layer-1 edge agg (2-wide)
    for (int t = tid; t < ke; t += 256) {
        int d = kedge[2 * t + 1];
        if ((d >> 6) == b) {
            int s = kedge[2 * t];
            float nm = rsqrtf(degs[s]) * rsqrtf(degs[d]);
            float2 h = h0s[s];
            atomicAdd(&psl[d & 63].x, nm * h.x);
            atomicAdd(&psl[d & 63].y, nm * h.y);
        }
    }
    __syncthreads();
    // layer-1 node -> tileA = h1
    for (int j = tid; j < nk * FD; j += 256) {
        int ld = j >> 7, f = j & 127, slot = b * SLOTC + ld;
        float di = rsqrtf(degs[slot]), d2 = di * di;
        float2 h = h0s[slot];
        float a0 = psl[ld].x + d2 * h.x;
        float a1 = psl[ld].y + d2 * h.y;
        float v = a0 * W1[f] + a1 * W1[FD + f] + b1[f];
        v = fmaxf(v, 0.f);
        v = (v - rm1[f]) * rsqrtf(rv1[f] + 1e-5f) * g1[f] + be1[f];
        tileA[j] = v;
    }
    __syncthreads();
    // mm2: tileB = tileA @ W2
    for (int j = tid; j < nk * FD; j += 256) {
        int ld = j >> 7, f = j & 127;
        const float* xr = tileA + ld * FD;
        float acc = 0.f;
        #pragma unroll 8
        for (int k = 0; k < FD; k++) acc += xr[k] * W2[k * FD + f];
        tileB[j] = acc;
    }
    __syncthreads();

    if (cross == 0) {
        // ---- fast path: all kept edges intra-graph; finish in LDS (round-0) ----
        for (int j = tid; j < nk * FD; j += 256) tileA[j] = 0.f;
        __syncthreads();
        for (long long idx = tid; idx < (long long)ke * FD; idx += 256) {
            int e = (int)(idx >> 7), f = (int)(idx & 127);
            int d = kedge[2 * e + 1];
            if ((d >> 6) == b) {
                int s = kedge[2 * e];            // cross==0 => s in graph b
                float nm = rsqrtf(degs[s]) * rsqrtf(degs[d]);
                atomicAdd(&tileA[(d & 63) * FD + f], nm * tileB[(s & 63) * FD + f]);
            }
        }
        __syncthreads();
        // bn2 -> tileA = h2
        for (int j = tid; j < nk * FD; j += 256) {
            int ld = j >> 7, f = j & 127, slot = b * SLOTC + ld;
            float di = rsqrtf(degs[slot]);
            float v = tileA[j] + di * di * tileB[j] + b2[f];
            v = fmaxf(v, 0.f);
            v = (v - rm2[f]) * rsqrtf(rv2[f] + 1e-5f) * g2[f] + be2[f];
            tileA[j] = v;
        }
        __syncthreads();
        // mm3: tileB = tileA @ W3
        for (int j = tid; j < nk * FD; j += 256) {
            int ld = j >> 7, f = j & 127;
            const float* xr = tileA + ld * FD;
            float acc = 0.f;
            #pragma unroll 8
            for (int k = 0; k < FD; k++) acc += xr[k] * W3[k * FD + f];
            tileB[j] = acc;
        }
        __syncthreads();
        // layer-3 scatter (LDS)
        for (int j = tid; j < nk * FD; j += 256) tileA[j] = 0.f;
        __syncthreads();
        for (long long idx = tid; idx < (long long)ke * FD; idx += 256) {
            int e = (int)(idx >> 7), f = (int)(idx & 127);
            int d = kedge[2 * e + 1];
            if ((d >> 6) == b) {
                int s = kedge[2 * e];
                float nm = rsqrtf(degs[s]) * rsqrtf(degs[d]);
                atomicAdd(&tileA[(d & 63) * FD + f], nm * tileB[(s & 63) * FD + f]);
            }
        }
        __syncthreads();
        // bn3 -> tileA = h3
        for (int j = tid; j < nk * FD; j += 256) {
            int ld = j >> 7, f = j & 127, slot = b * SLOTC + ld;
            float di = rsqrtf(degs[slot]);
            float v = tileA[j] + di * di * tileB[j] + b3[f];
            v = fmaxf(v, 0.f);
            v = (v - rm3[f]) * rsqrtf(rv3[f] + 1e-5f) * g3[f] + be3[f];
            tileA[j] = v;
        }
        __syncthreads();
        // pool + linear + log_softmax
        for (int f = tid; f < FD; f += 256) {
            float mx = -3.4028235e38f;
            for (int ld = 0; ld < nk; ld++) mx = fmaxf(mx, tileA[ld * FD + f]);
            poolv[f] = mx;
        }
        __syncthreads();
        if (tid == 0) {
            float z0 = linb[0], z1 = linb[1], z2 = linb[2];
            for (int f = 0; f < FD; f++) {
                float pv = poolv[f];
                z0 += pv * linW[f * 3 + 0];
                z1 += pv * linW[f * 3 + 1];
                z2 += pv * linW[f * 3 + 2];
            }
            float m = fmaxf(z0, fmaxf(z1, z2));
            float l = m + logf(expf(z0 - m) + expf(z1 - m) + expf(z2 - m));
            out[b * 3 + 0] = z0 - l;
            out[b * 3 + 1] = z1 - l;
            out[b * 3 + 2] = z2 - l;
        }
        return;
    }

    // ======== generic path (cross-graph kept edges exist; never taken with
    // this data — correctness only, self-sufficient, serial-over-edges) ======
    // Helper lambdas (uniform control flow: all loop bounds/indices read from
    // globals identically by all threads; __syncthreads inside is safe).
    auto hY_row = [&](int s) {               // rowY = hY row of arbitrary slot s
        if (tid == 0) aggs = make_float2(0.f, 0.f);
        __syncthreads();
        float a0 = 0.f, a1 = 0.f;
        for (int e = tid; e < ke; e += 256) {
            if (kedge[2 * e + 1] == s) {
                int u = kedge[2 * e];
                float nm = rsqrtf(degs[u]) * rsqrtf(degs[s]);
                float2 h = h0s[u];
                a0 += nm * h.x; a1 += nm * h.y;
            }
        }
        atomicAdd(&aggs.x, a0); atomicAdd(&aggs.y, a1);
        __syncthreads();
        float di = rsqrtf(degs[s]), d2 = di * di;
        float2 h = h0s[s];
        float A0 = aggs.x + d2 * h.x, A1 = aggs.y + d2 * h.y;
        for (int f = tid; f < FD; f += 256) {
            float v = A0 * W1[f] + A1 * W1[FD + f] + b1[f];
            v = fmaxf(v, 0.f);
            v = (v - rm1[f]) * rsqrtf(rv1[f] + 1e-5f) * g1[f] + be1[f];
            rowT[f] = v;
        }
        __syncthreads();
        for (int f = tid; f < FD; f += 256) {
            float acc = 0.f;
            for (int k = 0; k < FD; k++) acc += rowT[k] * W2[k * FD + f];
            rowY[f] = acc;
        }
        __syncthreads();
    };
    auto hYB_row = [&](int s) {              // rowB = (h2[s]) @ W3 for arbitrary s
        for (int f = tid; f < FD; f += 256) rowAgg[f] = 0.f;
        __syncthreads();
        for (int e = 0; e < ke; e++) {       // in-edges of s (serial, uniform)
            if (kedge[2 * e + 1] != s) continue;
            int u = kedge[2 * e];
            hY_row(u);                       // rowY = hY[u]
            float nm = rsqrtf(degs[u]) * rsqrtf(degs[s]);
            for (int f = tid; f < FD; f += 256) rowAgg[f] += nm * rowY[f];
            __syncthreads();
        }
        hY_row(s);                           // rowY = hY[s] (self term)
        float di = rsqrtf(degs[s]);
        for (int f = tid; f < FD; f += 256) {
            float v = rowAgg[f] + di * di * rowY[f] + b2[f];
            v = fmaxf(v, 0.f);
            v = (v - rm2[f]) * rsqrtf(rv2[f] + 1e-5f) * g2[f] + be2[f];
            rowH2[f] = v;
        }
        __syncthreads();
        for (int f = tid; f < FD; f += 256) {
            float acc = 0.f;
            for (int k = 0; k < FD; k++) acc += rowH2[k] * W3[k * FD + f];
            rowB[f] = acc;
        }
        __syncthreads();
    };

    // layer-2 agg into tileA (own hY rows from tileB; foreign recomputed)
    for (int j = tid; j < nk * FD; j += 256) tileA[j] = 0.f;
    __syncthreads();
    for (int e = 0; e < ke; e++) {
        int d = kedge[2 * e + 1];
        if ((d >> 6) != b) continue;
        int s = kedge[2 * e];
        float nm = rsqrtf(degs[s]) * rsqrtf(degs[d]);
        const float* srow;
        if ((s >> 6) == b) srow = &tileB[(s & 63) * FD];
        else { hY_row(s); srow = rowY; }
        for (int f = tid; f < FD; f += 256) tileA[(d & 63) * FD + f] += nm * srow[f];
        __syncthreads();
    }
    // bn2 -> tileA = h2_own (self term from tileB = hY_own)
    for (int j = tid; j < nk * FD; j += 256) {
        int ld = j >> 7, f = j & 127, slot = b * SLOTC + ld;
        float di = rsqrtf(degs[slot]);
        float v = tileA[j] + di * di * tileB[j] + b2[f];
        v = fmaxf(v, 0.f);
        v = (v - rm2[f]) * rsqrtf(rv2[f] + 1e-5f) * g2[f] + be2[f];
        tileA[j] = v;
    }
    __syncthreads();
    // mm3 -> tileB = hYB_own (overwrites hY_own; foreign needs recompute anyway)
    for (int j = tid; j < nk * FD; j += 256) {
        int ld = j >> 7, f = j & 127;
        const float* xr = tileA + ld * FD;
        float acc = 0.f;
        #pragma unroll 8
        for (int k = 0; k < FD; k++) acc += xr[k] * W3[k * FD + f];
        tileC[j] = acc;                      // stash hYB_own in tileC first
    }
    __syncthreads();
    for (int j = tid; j < nk * FD; j += 256) tileB[j] = tileC[j];
    __syncthreads();
    // layer-3 agg into tileC (own hYB from tileB; foreign via hYB_row)
    for (int j = tid; j < nk * FD; j += 256) tileC[j] = 0.f;
    __syncthreads();
    for (int e = 0; e < ke; e++) {
        int d = kedge[2 * e + 1];
        if ((d >> 6) != b) continue;
        int s = kedge[2 * e];
        float nm = rsqrtf(degs[s]) * rsqrtf(degs[d]);
        const float* srow;
        if ((s >> 6) == b) srow = &tileB[(s & 63) * FD];
        else { hYB_row(s); srow = rowB; }
        for (int f = tid; f < FD; f += 256) tileC[(d & 63) * FD + f] += nm * srow[f];
        __syncthreads();
    }
    // bn3 -> tileA = h3
    for (int j = tid; j < nk * FD; j += 256) {
        int ld = j >> 7, f = j & 127, slot = b * SLOTC + ld;
        float di = rsqrtf(degs[slot]);
        float v = tileC[j] + di * di * tileB[j] + b3[f];
        v = fmaxf(v, 0.f);
        v = (v - rm3[f]) * rsqrtf(rv3[f] + 1e-5f) * g3[f] + be3[f];
        tileA[j] = v;
    }
    __syncthreads();
    // pool + linear + log_softmax
    for (int f = tid; f < FD; f += 256) {
        float mx = -3.4028235e38f;
        for (int ld = 0; ld < nk; ld++) mx = fmaxf(mx, tileA[ld * FD + f]);
        poolv[f] = mx;
    }
    __syncthreads();
    if (tid == 0) {
        float z0 = linb[0], z1 = linb[1], z2 = linb[2];
        for (int f = 0; f < FD; f++) {
            float pv = poolv[f];
            z0 += pv * linW[f * 3 + 0];
            z1 += pv * linW[f * 3 + 1];
            z2 += pv * linW[f * 3 + 2];
        }
        float m = fmaxf(z0, fmaxf(z1, z2));
        float l = m + logf(expf(z0 - m) + expf(z1 - m) + expf(z2 - m));
        out[b * 3 + 0] = z0 - l;
        out[b * 3 + 1] = z1 - l;
        out[b * 3 + 2] = z2 - l;
    }
}

extern "C" void kernel_launch(void* const* d_in, const int* in_sizes, int n_in,
                              void* d_out, int out_size, void* d_ws, size_t ws_size,
                              hipStream_t stream) {
    (void)in_sizes; (void)n_in; (void)out_size; (void)ws_size;
    const float* x    = (const float*)d_in[0];
    const int*   ei   = (const int*)d_in[1];
    const int*   bidx = (const int*)d_in[2];
    const float* tw   = (const float*)d_in[3];
    const float* W1 = (const float*)d_in[4],  *b1 = (const float*)d_in[5],  *g1 = (const float*)d_in[6];
    const float* be1= (const float*)d_in[7],  *rm1= (const float*)d_in[8],  *rv1= (const float*)d_in[9];
    const float* W2 = (const float*)d_in[10], *b2 = (const float*)d_in[11], *g2 = (const float*)d_in[12];
    const float* be2= (const float*)d_in[13], *rm2= (const float*)d_in[14], *rv2= (const float*)d_in[15];
    const float* W3 = (const float*)d_in[16], *b3 = (const float*)d_in[17], *g3 = (const float*)d_in[18];
    const float* be3= (const float*)d_in[19], *rm3= (const float*)d_in[20], *rv3= (const float*)d_in[21];
    const float* linW = (const float*)d_in[22], *linb = (const float*)d_in[23];
    float* out = (float*)d_out;

    char* w = (char*)d_ws;
    auto take = [&](size_t bytes) { char* r = w; w += (bytes + 255) & ~(size_t)255; return r; };
    int*      kecnt  = (int*)take(16);        // [0]=total kept edges, [1]=cross
    int*      knt    = (int*)take((size_t)BB * 4);
    unsigned* kfbits = (unsigned*)take((size_t)NWORDS * 4);
    int*      nslot  = (int*)take((size_t)NN * 4);
    float*    degs   = (float*)take((size_t)KSLOTS * 4);
    float2*   h0s    = (float2*)take((size_t)KSLOTS * 8);
    int*      kedge  = (int*)take((size_t)EMAXE * 8);
    // ~8.7 MB

    k_scorekeep<<<BB, 256, 0, stream>>>((const float2*)x, bidx, tw,
                                        kfbits, nslot, knt, degs, h0s, kecnt);
    k_edges<<<(EE / 4 + 255) / 256, 256, 0, stream>>>((const int4*)ei, ei, kfbits,
                                                      nslot, degs, kedge, kecnt);
    k_tail<<<BB, 256, 0, stream>>>(degs, h0s, kedge, kecnt, knt,
                                   W1, b1, g1, be1, rm1, rv1,
                                   W2, b2, g2, be2, rm2, rv2,
                                   W3, b3, g3, be3, rm3, rv3,
                                   linW, linb, out);
}